// Round 10
// baseline (33.710 us; speedup 1.0000x reference)
//
#include <hip/hip_runtime.h>

constexpr int C_ = 1000;
constexpr int A_ = 512;
constexpr int N_ = 65536;
constexpr int CA_ = C_ * A_;
constexpr float ONE_MINUS_M = 0.2f;   // 1 - MOMENTUM

constexpr int TPB   = 512;            // 8 waves
constexpr int NW    = TPB / 64;       // 8 waves per block
constexpr int LPW   = N_ / NW;        // 8192 labels per wave
constexpr int ITERS = LPW / 4 / 64;   // 32 int4-iters per lane
constexpr int NBLK  = C_ / 2;         // 500 blocks, 2 classes each

__device__ __forceinline__ void acc_row(const float* __restrict__ rp,
                                        float4& s0, float4& s1,
                                        float4& q0, float4& q1)
{
    const float4 v0 = *reinterpret_cast<const float4*>(rp);
    const float4 v1 = *reinterpret_cast<const float4*>(rp + 4);
    s0.x += v0.x; s0.y += v0.y; s0.z += v0.z; s0.w += v0.w;
    s1.x += v1.x; s1.y += v1.y; s1.z += v1.z; s1.w += v1.w;
    q0.x = fmaf(v0.x, v0.x, q0.x); q0.y = fmaf(v0.y, v0.y, q0.y);
    q0.z = fmaf(v0.z, v0.z, q0.z); q0.w = fmaf(v0.w, v0.w, q0.w);
    q1.x = fmaf(v1.x, v1.x, q1.x); q1.y = fmaf(v1.y, v1.y, q1.y);
    q1.z = fmaf(v1.z, v1.z, q1.z); q1.w = fmaf(v1.w, v1.w, q1.w);
}

// R10: 2 classes per block (500 blocks). Each block scans all N labels ONCE
// for both classes (halves the redundant label L2 traffic vs 1000 blocks),
// gathers into two private accumulator sets, then runs the 8-wave combine +
// EMA finalize twice, reusing the same 32 KB LDS (keeps 3-4 blocks/CU).
__global__ __launch_bounds__(TPB, 6) void fused_kernel(
    const float* __restrict__ feat, const int* __restrict__ labels,
    const float* __restrict__ cov, const float* __restrict__ mean,
    const float* __restrict__ amount, float* __restrict__ out)
{
    __shared__ float lds_s[NW][A_];   // 16 KB (reused for both classes)
    __shared__ float lds_q[NW][A_];   // 16 KB
    __shared__ int   lds_cnt[NW];

    const int c0 = 2 * blockIdx.x;
    const int c1 = c0 + 1;
    const int wv = threadIdx.x >> 6;
    const int ln = threadIdx.x & 63;

    const int4* lab4  = reinterpret_cast<const int4*>(labels);
    const int   wbase = wv * (LPW / 4);    // int4 index base of this wave
    const int   colb  = ln * 8;            // this lane's 8 columns

    float4 sA0 = {0,0,0,0}, sA1 = {0,0,0,0}, qA0 = {0,0,0,0}, qA1 = {0,0,0,0};
    float4 sB0 = {0,0,0,0}, sB1 = {0,0,0,0}, qB0 = {0,0,0,0}, qB1 = {0,0,0,0};
    int cntA = 0, cntB = 0;

    int4 L = lab4[wbase + ln];             // prefetched
    for (int it = 0; it < ITERS; ++it) {
        int4 Ln = {0,0,0,0};
        if (it + 1 < ITERS) Ln = lab4[wbase + (it + 1) * 64 + ln];  // in flight

        const int lv[4] = {L.x, L.y, L.z, L.w};
        const int rbase = (wbase + it * 64) * 4;   // row of (bit b, comp k)

        #pragma unroll
        for (int comp = 0; comp < 4; ++comp) {
            unsigned long long mA = __ballot(lv[comp] == c0);
            unsigned long long mB = __ballot(lv[comp] == c1);
            cntA += (int)__popcll(mA);
            cntB += (int)__popcll(mB);
            while (mA) {                            // wave-uniform walks
                const int b = (int)__builtin_ctzll(mA);
                mA &= mA - 1;
                acc_row(feat + (size_t)(rbase + 4 * b + comp) * A_ + colb,
                        sA0, sA1, qA0, qA1);
            }
            while (mB) {
                const int b = (int)__builtin_ctzll(mB);
                mB &= mB - 1;
                acc_row(feat + (size_t)(rbase + 4 * b + comp) * A_ + colb,
                        sB0, sB1, qB0, qB1);
            }
        }
        L = Ln;
    }

    // ---- combine + finalize, class A then class B (LDS reused) ----
    #pragma unroll
    for (int j = 0; j < 2; ++j) {
        const int cj = (j == 0) ? c0 : c1;
        if (ln == 0) lds_cnt[wv] = (j == 0) ? cntA : cntB;
        if (j == 0) {
            *reinterpret_cast<float4*>(&lds_s[wv][colb])     = sA0;
            *reinterpret_cast<float4*>(&lds_s[wv][colb + 4]) = sA1;
            *reinterpret_cast<float4*>(&lds_q[wv][colb])     = qA0;
            *reinterpret_cast<float4*>(&lds_q[wv][colb + 4]) = qA1;
        } else {
            *reinterpret_cast<float4*>(&lds_s[wv][colb])     = sB0;
            *reinterpret_cast<float4*>(&lds_s[wv][colb + 4]) = sB1;
            *reinterpret_cast<float4*>(&lds_q[wv][colb])     = qB0;
            *reinterpret_cast<float4*>(&lds_q[wv][colb + 4]) = qB1;
        }
        __syncthreads();

        const int col = threadIdx.x;       // 512 threads -> 512 cols
        float s = 0.f, q = 0.f;
        #pragma unroll
        for (int w = 0; w < NW; ++w) { s += lds_s[w][col]; q += lds_q[w][col]; }
        int cntc = 0;
        #pragma unroll
        for (int w = 0; w < NW; ++w) cntc += lds_cnt[w];

        const float cntf = (float)cntc;
        const float safe = (cntc == 0) ? 1.f : cntf;
        const float inv  = 1.f / safe;
        const float ave  = s * inv;
        const float var  = fmaxf(q * inv - ave * ave, 0.f);

        const float amt   = amount[cj];
        const float den   = cntf + amt;
        const float w_raw = (den > 0.f) ? (cntf / den) : 0.f;
        const float w     = (w_raw > 0.f) ? fmaxf(w_raw, ONE_MINUS_M) : 0.f;
        const float omw   = 1.f - w;

        const int idx = cj * A_ + col;
        const float m  = mean[idx];
        const float cv = cov[idx];
        const float d  = m - ave;
        out[idx]       = cv * omw + var * w + w * omw * d * d;   // new_cov
        out[CA_ + idx] = m * omw + ave * w;                      // new_mean
        if (col == 0) out[2 * CA_ + cj] = amt + cntf;

        __syncthreads();   // lds_s/lds_q free for class B
    }
}

extern "C" void kernel_launch(void* const* d_in, const int* in_sizes, int n_in,
                              void* d_out, int out_size, void* d_ws, size_t ws_size,
                              hipStream_t stream)
{
    const float* feat   = (const float*)d_in[0];
    const int*   labels = (const int*)  d_in[1];
    const float* cov    = (const float*)d_in[2];
    const float* mean   = (const float*)d_in[3];
    const float* amount = (const float*)d_in[4];
    float* out = (float*)d_out;

    fused_kernel<<<NBLK, TPB, 0, stream>>>(feat, labels, cov, mean, amount, out);
}

// Round 11
// 30.911 us; speedup vs baseline: 1.0906x; 1.0906x over previous
//
#include <hip/hip_runtime.h>

constexpr int C_ = 1000;
constexpr int A_ = 512;
constexpr int N_ = 65536;
constexpr int CA_ = C_ * A_;
constexpr float ONE_MINUS_M = 0.2f;   // 1 - MOMENTUM

constexpr int TPB   = 512;            // 8 waves
constexpr int NW    = TPB / 64;       // 8 waves per block
constexpr int LPW   = N_ / NW;        // 8192 labels per wave
constexpr int ITERS = LPW / 4 / 64;   // 32 int4-iters per lane

// R11 = R9 (1000 blocks x 8 waves: exactly fills the 8192 wave slots;
// wave-autonomous ballot scan + whole-wave 2KB row gather, no mid-kernel
// barriers) + 1-deep PENDING-ROW pipeline: on a match, accumulate the
// previous pending row (loads issued >=1 match ago, ~200+ cycles in
// flight) and only then issue this row's loads. Converts the per-match
// load->FMA stall into overlap with the label scan.
__global__ __launch_bounds__(TPB, 8) void fused_kernel(
    const float* __restrict__ feat, const int* __restrict__ labels,
    const float* __restrict__ cov, const float* __restrict__ mean,
    const float* __restrict__ amount, float* __restrict__ out)
{
    __shared__ float lds_s[NW][A_];   // 16 KB
    __shared__ float lds_q[NW][A_];   // 16 KB
    __shared__ int   lds_cnt[NW];

    const int c  = blockIdx.x;
    const int wv = threadIdx.x >> 6;
    const int ln = threadIdx.x & 63;

    const int4* lab4  = reinterpret_cast<const int4*>(labels);
    const int   wbase = wv * (LPW / 4);    // int4 index base of this wave
    const int   colb  = ln * 8;            // this lane's 8 columns

    float4 s0 = {0,0,0,0}, s1 = {0,0,0,0};
    float4 q0 = {0,0,0,0}, q1 = {0,0,0,0};
    float4 p0 = {0,0,0,0}, p1 = {0,0,0,0};  // pending row
    bool   pend = false;                     // wave-uniform
    int cnt_w = 0;

    int4 L = lab4[wbase + ln];             // prefetched
    for (int it = 0; it < ITERS; ++it) {
        int4 Ln = {0,0,0,0};
        if (it + 1 < ITERS) Ln = lab4[wbase + (it + 1) * 64 + ln];  // in flight

        unsigned long long m[4];
        m[0] = __ballot(L.x == c);
        m[1] = __ballot(L.y == c);
        m[2] = __ballot(L.z == c);
        m[3] = __ballot(L.w == c);
        const int rbase = (wbase + it * 64) * 4;   // row of (bit b, comp k)

        #pragma unroll
        for (int comp = 0; comp < 4; ++comp) {
            unsigned long long mm = m[comp];
            cnt_w += (int)__popcll(mm);
            while (mm) {                            // wave-uniform walk
                const int b = (int)__builtin_ctzll(mm);
                mm &= mm - 1;
                const int row = rbase + 4 * b + comp;
                const float* rp = feat + (size_t)row * A_ + colb;
                if (pend) {                         // retire previous row
                    s0.x += p0.x; s0.y += p0.y; s0.z += p0.z; s0.w += p0.w;
                    s1.x += p1.x; s1.y += p1.y; s1.z += p1.z; s1.w += p1.w;
                    q0.x = fmaf(p0.x, p0.x, q0.x); q0.y = fmaf(p0.y, p0.y, q0.y);
                    q0.z = fmaf(p0.z, p0.z, q0.z); q0.w = fmaf(p0.w, p0.w, q0.w);
                    q1.x = fmaf(p1.x, p1.x, q1.x); q1.y = fmaf(p1.y, p1.y, q1.y);
                    q1.z = fmaf(p1.z, p1.z, q1.z); q1.w = fmaf(p1.w, p1.w, q1.w);
                }
                p0 = *reinterpret_cast<const float4*>(rp);      // issue new loads
                p1 = *reinterpret_cast<const float4*>(rp + 4);
                pend = true;
            }
        }
        L = Ln;
    }
    if (pend) {                                     // retire last row
        s0.x += p0.x; s0.y += p0.y; s0.z += p0.z; s0.w += p0.w;
        s1.x += p1.x; s1.y += p1.y; s1.z += p1.z; s1.w += p1.w;
        q0.x = fmaf(p0.x, p0.x, q0.x); q0.y = fmaf(p0.y, p0.y, q0.y);
        q0.z = fmaf(p0.z, p0.z, q0.z); q0.w = fmaf(p0.w, p0.w, q0.w);
        q1.x = fmaf(p1.x, p1.x, q1.x); q1.y = fmaf(p1.y, p1.y, q1.y);
        q1.z = fmaf(p1.z, p1.z, q1.z); q1.w = fmaf(p1.w, p1.w, q1.w);
    }

    // ---- single combine: 8 waves x 512 cols ----
    if (ln == 0) lds_cnt[wv] = cnt_w;      // wave-uniform value
    *reinterpret_cast<float4*>(&lds_s[wv][colb])     = s0;
    *reinterpret_cast<float4*>(&lds_s[wv][colb + 4]) = s1;
    *reinterpret_cast<float4*>(&lds_q[wv][colb])     = q0;
    *reinterpret_cast<float4*>(&lds_q[wv][colb + 4]) = q1;
    __syncthreads();

    const int col = threadIdx.x;           // 512 threads -> 512 cols
    float s = 0.f, q = 0.f;
    #pragma unroll
    for (int w = 0; w < NW; ++w) { s += lds_s[w][col]; q += lds_q[w][col]; }
    int cntc = 0;
    #pragma unroll
    for (int w = 0; w < NW; ++w) cntc += lds_cnt[w];

    const float cntf = (float)cntc;
    const float safe = (cntc == 0) ? 1.f : cntf;
    const float inv  = 1.f / safe;
    const float ave  = s * inv;
    const float var  = fmaxf(q * inv - ave * ave, 0.f);

    const float amt   = amount[c];
    const float den   = cntf + amt;
    const float w_raw = (den > 0.f) ? (cntf / den) : 0.f;
    const float w     = (w_raw > 0.f) ? fmaxf(w_raw, ONE_MINUS_M) : 0.f;
    const float omw   = 1.f - w;

    const int idx = c * A_ + col;
    const float m  = mean[idx];
    const float cv = cov[idx];
    const float d  = m - ave;
    out[idx]       = cv * omw + var * w + w * omw * d * d;   // new_cov
    out[CA_ + idx] = m * omw + ave * w;                      // new_mean
    if (col == 0) out[2 * CA_ + c] = amt + cntf;
}

extern "C" void kernel_launch(void* const* d_in, const int* in_sizes, int n_in,
                              void* d_out, int out_size, void* d_ws, size_t ws_size,
                              hipStream_t stream)
{
    const float* feat   = (const float*)d_in[0];
    const int*   labels = (const int*)  d_in[1];
    const float* cov    = (const float*)d_in[2];
    const float* mean   = (const float*)d_in[3];
    const float* amount = (const float*)d_in[4];
    float* out = (float*)d_out;

    fused_kernel<<<C_, TPB, 0, stream>>>(feat, labels, cov, mean, amount, out);
}